// Round 17
// baseline (331.456 us; speedup 1.0000x reference)
//
#include <hip/hip_runtime.h>
#include <hip/hip_bf16.h>
#include <stdint.h>
#include <math.h>

#define BATCH 128
#define NTOK 245
#define HEADS 12
#define DHEAD 64
#define CDIM 768
#define KT 24          // CDIM/32 k-tiles
#define SUBT 512       // ushorts per (rowtile,ktile) subtile = 64 slots * 8
#define BSTR (KT*64*8) // ushorts per rowtile stripe = 12288
#define SCL 0.18033688f      // 0.125 * log2(e)
#define PCLAMP 43.3f         // 30 * log2(e)

typedef __attribute__((ext_vector_type(8))) short short8;
typedef __attribute__((ext_vector_type(4))) float f32x4;

__device__ __forceinline__ float bf2f(uint32_t hbits) {
    union { uint32_t u; float f; } v; v.u = hbits << 16; return v.f;
}
__device__ __forceinline__ uint32_t f2bf(float f) {
    union { float f; uint32_t u; } v; v.f = f;
    return (v.u + 0x7fffu + ((v.u >> 16) & 1u)) >> 16;
}
__device__ __forceinline__ ushort2 pk2bf(float x, float y) {
    union { __hip_bfloat162 h; ushort2 u; } c;
    c.h = __float22bfloat162_rn(make_float2(x, y));
    return c.u;
}
// fragment-tiled global address for element (row m, col k) of a [R][768] matrix
__device__ __forceinline__ size_t tiled_addr(int m, int k) {
    return (((size_t)(m >> 4) * KT + (k >> 5)) * 64 + ((k >> 3) & 3) * 16 + (m & 15)) * 8
           + (k & 7);
}
// async global->LDS, 16B/lane; LDS dest wave-uniform, global src per-lane.
__device__ __forceinline__ void gl_lds16(const uint16_t* g, ushort* lds) {
    __builtin_amdgcn_global_load_lds(
        (const __attribute__((address_space(1))) void*)g,
        (__attribute__((address_space(3))) void*)lds,
        16, 0, 0);
}

// =============== Kernel A: fused fp32->bf16 convert + fragment-tile repack =
#define N8_X  3010560   // 24,084,480 / 8
#define N8_WQ  221184   //  1,769,472 / 8
#define N8_WP   73728   //    589,824 / 8
__global__ __launch_bounds__(256)
void cvt_all(const float* __restrict__ x, const float* __restrict__ wq,
             const float* __restrict__ wp, uint16_t* __restrict__ xd,
             uint16_t* __restrict__ wqd, uint16_t* __restrict__ wpd)
{
    int i = blockIdx.x * 256 + threadIdx.x;
    const int stride = gridDim.x * 256;
    const int total = N8_X + N8_WQ + N8_WP;
    for (; i < total; i += stride) {
        const float* src; uint16_t* dst; int j;
        if (i < N8_X)              { src = x;  dst = xd;  j = i; }
        else if (i < N8_X + N8_WQ) { src = wq; dst = wqd; j = i - N8_X; }
        else                       { src = wp; dst = wpd; j = i - N8_X - N8_WQ; }
        const int sl = j & 63;
        const int tile = j >> 6;
        const int rt = tile / KT, kt = tile - rt * KT;
        const size_t soff = (size_t)(rt * 16 + (sl & 15)) * CDIM + kt * 32 + (sl >> 4) * 8;
        float4 a = *(const float4*)(src + soff);
        float4 b = *(const float4*)(src + soff + 4);
        ushort2 p0 = pk2bf(a.x, a.y), p1 = pk2bf(a.z, a.w);
        ushort2 p2 = pk2bf(b.x, b.y), p3 = pk2bf(b.z, b.w);
        uint4 o;
        o.x = (uint32_t)p0.x | ((uint32_t)p0.y << 16);
        o.y = (uint32_t)p1.x | ((uint32_t)p1.y << 16);
        o.z = (uint32_t)p2.x | ((uint32_t)p2.y << 16);
        o.w = (uint32_t)p3.x | ((uint32_t)p3.y << 16);
        *(uint4*)(dst + (size_t)j * 8) = o;
    }
}

// =============== Kernel 0: bias precompute (pre-scaled by log2 e) ==========
__global__ __launch_bounds__(256)
void bias_pre(const float* __restrict__ bias_table, const int* __restrict__ rel,
              int n_bias, uint16_t* __restrict__ bias_t)
{
    const int h = blockIdx.x, j = blockIdx.y, q = threadIdx.x;
    float v = -43281.f;   // -30000 * log2(e): pad -> exp2 underflows to 0
    if (j < NTOK && q < NTOK)
        v = bias_table[(size_t)h * n_bias + rel[q * NTOK + j]] * 1.44269504f;
    bias_t[((size_t)h * 256 + j) * 256 + q] = (uint16_t)f2bf(v);
}

// =============== GEMM core loop: A via LDS (3-buf, counted vmcnt), ========
// B direct from global (L2-resident, fragment-tiled = coalesced 1KB/read),
// register double-buffered one k-tile ahead.
// VMEM per iter: 2 A-DMA + 4 B-loads = 6 -> vmcnt(6) guarantees A(t) landed.
// WAR on A: re-staged 2 iters after read, behind lgkmcnt(0)+barrier.
#define GEMM_LOOP_BDIR                                                           \
    gl_lds16(gA0,        &Af[0][w  ][0][0]);                                     \
    gl_lds16(gA1,        &Af[0][w+4][0][0]);                                     \
    gl_lds16(gA0 + SUBT, &Af[1][w  ][0][0]);                                     \
    gl_lds16(gA1 + SUBT, &Af[1][w+4][0][0]);                                     \
    short8 bc0 = *(const short8*)(gB);                                           \
    short8 bc1 = *(const short8*)(gB + BSTR);                                    \
    short8 bc2 = *(const short8*)(gB + 2*BSTR);                                  \
    short8 bc3 = *(const short8*)(gB + 3*BSTR);                                  \
    short8 bn0, bn1, bn2, bn3;                                                   \
    int cur = 0, nxt = 2;                                                        \
    _Pragma("unroll 1")                                                          \
    for (int t = 0; t < KT; ++t) {                                               \
        if (t == KT - 1) { asm volatile("s_waitcnt vmcnt(0) lgkmcnt(0)" ::: "memory"); } \
        else             { asm volatile("s_waitcnt vmcnt(6) lgkmcnt(0)" ::: "memory"); } \
        __builtin_amdgcn_s_barrier();                                            \
        if (t + 2 < KT) {                                                        \
            const int ko = (t + 2) * SUBT;                                       \
            gl_lds16(gA0 + ko, &Af[nxt][w  ][0][0]);                             \
            gl_lds16(gA1 + ko, &Af[nxt][w+4][0][0]);                             \
        }                                                                        \
        if (t + 1 < KT) {                                                        \
            const uint16_t* gbn = gB + (t + 1) * SUBT;                           \
            bn0 = *(const short8*)(gbn);                                         \
            bn1 = *(const short8*)(gbn + BSTR);                                  \
            bn2 = *(const short8*)(gbn + 2*BSTR);                                \
            bn3 = *(const short8*)(gbn + 3*BSTR);                                \
        }                                                                        \
        short8 af[4];                                                            \
        _Pragma("unroll")                                                        \
        for (int m = 0; m < 4; ++m)                                              \
            af[m] = *(const short8*)&Af[cur][wr*4 + m][l][0];                    \
        _Pragma("unroll")                                                        \
        for (int m = 0; m < 4; ++m) {                                            \
            acc[m][0] = __builtin_amdgcn_mfma_f32_16x16x32_bf16(bc0, af[m], acc[m][0], 0, 0, 0); \
            acc[m][1] = __builtin_amdgcn_mfma_f32_16x16x32_bf16(bc1, af[m], acc[m][1], 0, 0, 0); \
            acc[m][2] = __builtin_amdgcn_mfma_f32_16x16x32_bf16(bc2, af[m], acc[m][2], 0, 0, 0); \
            acc[m][3] = __builtin_amdgcn_mfma_f32_16x16x32_bf16(bc3, af[m], acc[m][3], 0, 0, 0); \
        }                                                                        \
        if (t + 1 < KT) { bc0 = bn0; bc1 = bn1; bc2 = bn2; bc3 = bn3; }          \
        cur = (cur == 2) ? 0 : cur + 1;                                          \
        nxt = (nxt == 2) ? 0 : nxt + 1;                                          \
    }

// =============== Kernel 1: QKV projection (BM=BN=128) ======================
__global__ __launch_bounds__(256)
void qkv_gemm_mfma(const uint16_t* __restrict__ xb, const uint16_t* __restrict__ wq,
                   uint16_t* __restrict__ qkv)
{
    __shared__ ushort Af[3][8][64][8];   // 24 KB (A only; B direct from L2)
    const int t = threadIdx.x;
    const int w = t >> 6, l = t & 63;
    const int wr = w >> 1, wc = w & 1;
    const int lm = l & 15, lk = l >> 4;

    // grid 4410, chunked-XCD swizzle (q=551, r=2)
    const int bid = blockIdx.x;
    const int xcd = bid & 7;
    const int wg = (xcd < 2 ? xcd * 552 : 1104 + (xcd - 2) * 551) + (bid >> 3);
    const int mtile = wg / 18, ctile = wg - mtile * 18;
    const int m0 = mtile * 128, c0 = ctile * 128;

    const uint16_t* gA0 = xb + ((size_t)(mtile*8 + w    ) * KT * 64 + l) * 8;
    const uint16_t* gA1 = xb + ((size_t)(mtile*8 + w + 4) * KT * 64 + l) * 8;
    const uint16_t* gB  = wq + ((size_t)(ctile*8 + wc*4) * KT * 64 + l) * 8;

    f32x4 acc[4][4];
    #pragma unroll
    for (int m = 0; m < 4; ++m)
        #pragma unroll
        for (int n = 0; n < 4; ++n) acc[m][n] = (f32x4){0.f,0.f,0.f,0.f};

    GEMM_LOOP_BDIR

    int sArr[4], hArr[4], dArr[4];
    #pragma unroll
    for (int n = 0; n < 4; ++n) {
        int c = c0 + wc*64 + n*16 + lk*4;
        int s = c / CDIM; int rem = c - s * CDIM;
        sArr[n] = s; hArr[n] = rem >> 6; dArr[n] = rem & 63;
    }
    #pragma unroll
    for (int m = 0; m < 4; ++m) {
        int gm  = m0 + wr*64 + m*16 + lm;
        int b   = gm / NTOK;
        int tok = gm - b * NTOK;
        #pragma unroll
        for (int n = 0; n < 4; ++n) {
            ushort2 u0 = pk2bf(acc[m][n][0], acc[m][n][1]);
            ushort2 u1 = pk2bf(acc[m][n][2], acc[m][n][3]);
            uint2 pk;
            pk.x = (uint32_t)u0.x | ((uint32_t)u0.y << 16);
            pk.y = (uint32_t)u1.x | ((uint32_t)u1.y << 16);
            size_t addr = ((((size_t)b*3 + sArr[n])*HEADS + hArr[n])*NTOK + tok)*DHEAD + dArr[n];
            *(uint2*)(qkv + addr) = pk;
        }
    }
}

// =============== Kernel 2: MFMA flash attention per (b,h) ==================
// Single-stage K/V (89 KB LDS). Fixed-reference softmax in exp2 domain;
// pads (bias=-43281) underflow to 0.
__global__ __launch_bounds__(512)
void attn_mfma(const uint16_t* __restrict__ qkv, const uint16_t* __restrict__ bias_t,
               uint16_t* __restrict__ o_t)
{
    __shared__ ushort Ks[256][72];    // 36864 B
    __shared__ ushort Vt[64][264];    // 33792 B
    __shared__ ushort Ps[8][16][72];  // 18432 B
    const int bh = blockIdx.x;
    const int b = bh / HEADS, h = bh % HEADS;
    const int t = threadIdx.x;
    const int w = t >> 6, l = t & 63;
    const int lm = l & 15, lk = l >> 4;
    const int wq0 = w * 32;

    const uint16_t* qbase = qkv + (((size_t)b*3 + 0)*HEADS + h) * (NTOK*DHEAD);
    const uint16_t* kbase = qkv + (((size_t)b*3 + 1)*HEADS + h) * (NTOK*DHEAD);
    const uint16_t* vbase = qkv + (((size_t)b*3 + 2)*HEADS + h) * (NTOK*DHEAD);
    const uint16_t* btab  = bias_t + (size_t)h * 256 * 256;

    {
        const int col = (t & 7) * 8;
        #pragma unroll
        for (int p = 0; p < 4; ++p) {
            int row = p * 64 + (t >> 3);
            uint4 val = make_uint4(0u,0u,0u,0u);
            if (row < NTOK) val = *(const uint4*)(kbase + (size_t)row * DHEAD + col);
            *(uint4*)&Ks[row][col] = val;
        }
    }
    {
        const int j  = t >> 1;
        const int dh = (t & 1) * 32;
        uint4 r0 = make_uint4(0,0,0,0), r1 = r0, r2 = r0, r3 = r0;
        if (j < NTOK) {
            const uint16_t* src = vbase + (size_t)j * DHEAD + dh;
            r0 = *(const uint4*)(src);
            r1 = *(const uint4*)(src + 8);
            r2 = *(const uint4*)(src + 16);
            r3 = *(const uint4*)(src + 24);
        }
        union { uint4 v[4]; ushort s[32]; } u;
        u.v[0] = r0; u.v[1] = r1; u.v[2] = r2; u.v[3] = r3;
        #pragma unroll
        for (int i = 0; i < 32; ++i)
            Vt[dh + i][j] = u.s[i];
    }

    short8 qf[2][2];
    #pragma unroll
    for (int m = 0; m < 2; ++m) {
        int qrow = wq0 + m*16 + lm; if (qrow > NTOK-1) qrow = NTOK-1;
        #pragma unroll
        for (int k2 = 0; k2 < 2; ++k2)
            qf[m][k2] = *(const short8*)(qbase + (size_t)qrow * DHEAD + k2*32 + lk*8);
    }

    f32x4 acc_o[2][4];
    float lsum[2][4];
    #pragma unroll
    for (int m = 0; m < 2; ++m) {
        #pragma unroll
        for (int n = 0; n < 4; ++n) acc_o[m][n] = (f32x4){0.f,0.f,0.f,0.f};
        #pragma unroll
        for (int r = 0; r < 4; ++r) lsum[m][r] = 0.f;
    }

    __syncthreads();

    for (int jb = 0; jb < 4; ++jb) {
        short8 kf[4][2], vf[4][2];
        #pragma unroll
        for (int n = 0; n < 4; ++n)
            #pragma unroll
            for (int k2 = 0; k2 < 2; ++k2) {
                kf[n][k2] = *(const short8*)&Ks[jb*64 + n*16 + lm][k2*32 + lk*8];
                vf[n][k2] = *(const short8*)&Vt[n*16 + lm][jb*64 + k2*32 + lk*8];
            }

        #pragma unroll
        for (int m = 0; m < 2; ++m) {
            f32x4 sv[4];
            __builtin_amdgcn_s_setprio(1);
            #pragma unroll
            for (int n = 0; n < 4; ++n) {
                f32x4 z = (f32x4){0.f,0.f,0.f,0.f};
                sv[n] = __builtin_amdgcn_mfma_f32_16x16x32_bf16(qf[m][0], kf[n][0], z, 0, 0, 0);
                sv[n] = __builtin_amdgcn_mfma_f32_16x16x32_bf16(qf[m][1], kf[n][1], sv[n], 0, 0, 0);
            }
            __builtin_amdgcn_s_setprio(0);
            #pragma unroll
            for (int n = 0; n < 4; ++n) {
                uint2 bb = *(const uint2*)(btab + (size_t)(jb*64 + n*16 + lm) * 256 + wq0 + m*16 + lk*4);
                float s0 = fmaf(sv[n][0], SCL, bf2f(bb.x & 0xffffu));
                float s1 = fmaf(sv[n][1], SCL, bf2f(bb.x >> 16));
                float s2 = fmaf(sv[n][2], SCL, bf2f(bb.y & 0xffffu));
                float s3 = fmaf(sv[n][3], SCL, bf2f(bb.y >> 16));
                sv[n][0] = exp2f(fminf(s0, PCLAMP));
                sv[n][1] = exp2f(fminf(s1, PCLAMP));
                sv[n][2] = exp2f(fminf(s2, PCLAMP));
                sv[n][3] = exp2f(fminf(s3, PCLAMP));
            }
            #pragma unroll
            for (int n = 0; n < 4; ++n)
                #pragma unroll
                for (int r = 0; r < 4; ++r) {
                    ushort u = pk2bf(sv[n][r], sv[n][r]).x;
                    lsum[m][r] += bf2f(u);
                    Ps[w][lk*4 + r][n*16 + lm] = u;
                }
            short8 pf[2];
            #pragma unroll
            for (int k2 = 0; k2 < 2; ++k2)
                pf[k2] = *(const short8*)&Ps[w][lm][k2*32 + lk*8];
            __builtin_amdgcn_s_setprio(1);
            #pragma unroll
            for (int n = 0; n < 4; ++n) {
                acc_o[m][n] = __builtin_amdgcn_mfma_f32_16x16x32_bf16(pf[0], vf[n][0], acc_o[m][n], 0, 0, 0);
                acc_o[m][n] = __builtin_amdgcn_mfma_f32_16x16x32_bf16(pf[1], vf[n][1], acc_o[m][n], 0, 0, 0);
            }
            __builtin_amdgcn_s_setprio(0);
        }
    }

    #pragma unroll
    for (int m = 0; m < 2; ++m) {
        float inv[4];
        #pragma unroll
        for (int r = 0; r < 4; ++r) {
            float s = lsum[m][r];
            s += __shfl_xor(s, 1);
            s += __shfl_xor(s, 2);
            s += __shfl_xor(s, 4);
            s += __shfl_xor(s, 8);
            inv[r] = 1.f / s;
        }
        #pragma unroll
        for (int r = 0; r < 4; ++r) {
            int q = wq0 + m*16 + lk*4 + r;
            if (q < NTOK) {
                int gm = b * NTOK + q;
                #pragma unroll
                for (int n = 0; n < 4; ++n) {
                    int k = h * DHEAD + n*16 + lm;
                    o_t[tiled_addr(gm, k)] = (uint16_t)f2bf(acc_o[m][n][r] * inv[r]);
                }
            }
        }
    }
}

// =============== Kernel 3: output projection (BM=BN=128) ===================
__global__ __launch_bounds__(256)
void proj_gemm_mfma(const uint16_t* __restrict__ ot, const uint16_t* __restrict__ wp,
                    const float* __restrict__ bias, float* __restrict__ out)
{
    __shared__ ushort Af[3][8][64][8];   // 24 KB
    const int t = threadIdx.x;
    const int w = t >> 6, l = t & 63;
    const int wr = w >> 1, wc = w & 1;
    const int lm = l & 15, lk = l >> 4;

    // grid 1470, chunked-XCD swizzle (q=183, r=6)
    const int bid = blockIdx.x;
    const int xcd = bid & 7;
    const int wg = (xcd < 6 ? xcd * 184 : 1104 + (xcd - 6) * 183) + (bid >> 3);
    const int mtile = wg / 6, ctile = wg - mtile * 6;
    const int m0 = mtile * 128, c0 = ctile * 128;

    const uint16_t* gA0 = ot + ((size_t)(mtile*8 + w    ) * KT * 64 + l) * 8;
    const uint16_t* gA1 = ot + ((size_t)(mtile*8 + w + 4) * KT * 64 + l) * 8;
    const uint16_t* gB  = wp + ((size_t)(ctile*8 + wc*4) * KT * 64 + l) * 8;

    f32x4 acc[4][4];
    #pragma unroll
    for (int m = 0; m < 4; ++m)
        #pragma unroll
        for (int n = 0; n < 4; ++n) acc[m][n] = (f32x4){0.f,0.f,0.f,0.f};

    GEMM_LOOP_BDIR

    float4 bsv[4]; int cArr[4];
    #pragma unroll
    for (int n = 0; n < 4; ++n) {
        cArr[n] = c0 + wc*64 + n*16 + lk*4;
        bsv[n]  = *(const float4*)(bias + cArr[n]);
    }
    #pragma unroll
    for (int m = 0; m < 4; ++m) {
        int gm = m0 + wr*64 + m*16 + lm;
        #pragma unroll
        for (int n = 0; n < 4; ++n) {
            float4 r;
            r.x = acc[m][n][0] + bsv[n].x;
            r.y = acc[m][n][1] + bsv[n].y;
            r.z = acc[m][n][2] + bsv[n].z;
            r.w = acc[m][n][3] + bsv[n].w;
            *(float4*)(out + (size_t)gm * CDIM + cArr[n]) = r;
        }
    }
}

extern "C" void kernel_launch(void* const* d_in, const int* in_sizes, int n_in,
                              void* d_out, int out_size, void* d_ws, size_t ws_size,
                              hipStream_t stream)
{
    (void)n_in; (void)out_size;
    const float* x          = (const float*)d_in[0];
    const float* qkv_w      = (const float*)d_in[1];
    const float* proj_w     = (const float*)d_in[2];
    const float* proj_b     = (const float*)d_in[3];
    const float* bias_table = (const float*)d_in[4];
    const int*   rel        = (const int*)d_in[5];
    const int n_bias = in_sizes[4] / HEADS;

    const size_t qkv_elems = (size_t)BATCH * 3 * HEADS * NTOK * DHEAD;  // 72,253,440
    const size_t o_elems   = (size_t)BATCH * HEADS * NTOK * DHEAD;      // 24,084,480 (= x elems)
    const size_t bt_elems  = (size_t)HEADS * 256 * 256;                 //    786,432
    const size_t wq_elems  = (size_t)3 * CDIM * CDIM;                   //  1,769,472
    const size_t wp_elems  = (size_t)CDIM * CDIM;                       //    589,824

    uint16_t* qkv_ws = (uint16_t*)d_ws;
    uint16_t* o_ws   = qkv_ws + qkv_elems;   // x_tiled until attn overwrites with O_tiled
    uint16_t* bt_ws  = o_ws + o_elems;
    uint16_t* wq_ws  = bt_ws + bt_elems;
    uint16_t* wp_ws  = wq_ws + wq_elems;
    const size_t need = (qkv_elems + o_elems + bt_elems + wq_elems + wp_elems) * sizeof(uint16_t);
    if (ws_size < need) return;   // ~199 MB

    uint16_t* xb = o_ws;

    cvt_all<<<2048, 256, 0, stream>>>(x, qkv_w, proj_w, xb, wq_ws, wp_ws);

    bias_pre<<<dim3(HEADS, 256), 256, 0, stream>>>(bias_table, rel, n_bias, bt_ws);

    qkv_gemm_mfma<<<4410, 256, 0, stream>>>(xb, wq_ws, qkv_ws);

    attn_mfma<<<dim3(BATCH * HEADS), 512, 0, stream>>>(qkv_ws, bt_ws, o_ws);

    proj_gemm_mfma<<<1470, 256, 0, stream>>>(o_ws, wp_ws, proj_b, (float*)d_out);
}

// Round 18
// 321.508 us; speedup vs baseline: 1.0309x; 1.0309x over previous
//
#include <hip/hip_runtime.h>
#include <hip/hip_bf16.h>
#include <stdint.h>
#include <math.h>

#define BATCH 128
#define NTOK 245
#define HEADS 12
#define DHEAD 64
#define CDIM 768
#define KT 24          // CDIM/32 k-tiles
#define SUBT 512       // ushorts per (rowtile,ktile) subtile = 64 slots * 8
#define SCL 0.18033688f      // 0.125 * log2(e)
#define PCLAMP 43.3f         // 30 * log2(e)

typedef __attribute__((ext_vector_type(8))) short short8;
typedef __attribute__((ext_vector_type(4))) float f32x4;

__device__ __forceinline__ float bf2f(uint32_t hbits) {
    union { uint32_t u; float f; } v; v.u = hbits << 16; return v.f;
}
__device__ __forceinline__ uint32_t f2bf(float f) {
    union { float f; uint32_t u; } v; v.f = f;
    return (v.u + 0x7fffu + ((v.u >> 16) & 1u)) >> 16;
}
__device__ __forceinline__ ushort2 pk2bf(float x, float y) {
    union { __hip_bfloat162 h; ushort2 u; } c;
    c.h = __float22bfloat162_rn(make_float2(x, y));
    return c.u;
}
// fragment-tiled global address for element (row m, col k) of a [R][768] matrix
__device__ __forceinline__ size_t tiled_addr(int m, int k) {
    return (((size_t)(m >> 4) * KT + (k >> 5)) * 64 + ((k >> 3) & 3) * 16 + (m & 15)) * 8
           + (k & 7);
}
// async global->LDS, 16B/lane; LDS dest wave-uniform, global src per-lane.
__device__ __forceinline__ void gl_lds16(const uint16_t* g, ushort* lds) {
    __builtin_amdgcn_global_load_lds(
        (const __attribute__((address_space(1))) void*)g,
        (__attribute__((address_space(3))) void*)lds,
        16, 0, 0);
}

// =============== Kernel A: fused fp32->bf16 convert + fragment-tile repack =
// Three segments (x, qkv_w, proj_w) in one launch so they overlap on-chip.
#define N8_X  3010560   // 24,084,480 / 8
#define N8_WQ  221184   //  1,769,472 / 8
#define N8_WP   73728   //    589,824 / 8
__global__ __launch_bounds__(256)
void cvt_all(const float* __restrict__ x, const float* __restrict__ wq,
             const float* __restrict__ wp, uint16_t* __restrict__ xd,
             uint16_t* __restrict__ wqd, uint16_t* __restrict__ wpd)
{
    int i = blockIdx.x * 256 + threadIdx.x;
    const int stride = gridDim.x * 256;
    const int total = N8_X + N8_WQ + N8_WP;
    for (; i < total; i += stride) {
        const float* src; uint16_t* dst; int j;
        if (i < N8_X)              { src = x;  dst = xd;  j = i; }
        else if (i < N8_X + N8_WQ) { src = wq; dst = wqd; j = i - N8_X; }
        else                       { src = wp; dst = wpd; j = i - N8_X - N8_WQ; }
        const int sl = j & 63;
        const int tile = j >> 6;
        const int rt = tile / KT, kt = tile - rt * KT;
        const size_t soff = (size_t)(rt * 16 + (sl & 15)) * CDIM + kt * 32 + (sl >> 4) * 8;
        float4 a = *(const float4*)(src + soff);
        float4 b = *(const float4*)(src + soff + 4);
        ushort2 p0 = pk2bf(a.x, a.y), p1 = pk2bf(a.z, a.w);
        ushort2 p2 = pk2bf(b.x, b.y), p3 = pk2bf(b.z, b.w);
        uint4 o;
        o.x = (uint32_t)p0.x | ((uint32_t)p0.y << 16);
        o.y = (uint32_t)p1.x | ((uint32_t)p1.y << 16);
        o.z = (uint32_t)p2.x | ((uint32_t)p2.y << 16);
        o.w = (uint32_t)p3.x | ((uint32_t)p3.y << 16);
        *(uint4*)(dst + (size_t)j * 8) = o;
    }
}

// =============== Kernel 0: bias precompute (pre-scaled by log2 e) ==========
__global__ __launch_bounds__(256)
void bias_pre(const float* __restrict__ bias_table, const int* __restrict__ rel,
              int n_bias, uint16_t* __restrict__ bias_t)
{
    const int h = blockIdx.x, j = blockIdx.y, q = threadIdx.x;
    float v = -43281.f;   // -30000 * log2(e): pad -> exp2 underflows to 0
    if (j < NTOK && q < NTOK)
        v = bias_table[(size_t)h * n_bias + rel[q * NTOK + j]] * 1.44269504f;
    bias_t[((size_t)h * 256 + j) * 256 + q] = (uint16_t)f2bf(v);
}

// =============== GEMM core loop (3-buf rotation, counted vmcnt) ============
// RAW: tile t staged at iter t-2; vmcnt(4) retires the 4 oldest loads.
// WAR: buffer re-staged only after a barrier whose lgkmcnt(0) drained all
//      waves' reads of it.
#define GEMM_LOOP                                                                \
    gl_lds16(gA0, &Af[0][w  ][0][0]);                                            \
    gl_lds16(gA1, &Af[0][w+4][0][0]);                                            \
    gl_lds16(gB0, &Bf[0][w  ][0][0]);                                            \
    gl_lds16(gB1, &Bf[0][w+4][0][0]);                                            \
    gl_lds16(gA0 + SUBT, &Af[1][w  ][0][0]);                                     \
    gl_lds16(gA1 + SUBT, &Af[1][w+4][0][0]);                                     \
    gl_lds16(gB0 + SUBT, &Bf[1][w  ][0][0]);                                     \
    gl_lds16(gB1 + SUBT, &Bf[1][w+4][0][0]);                                     \
    int cur = 0, nxt = 2;                                                        \
    _Pragma("unroll 1")                                                          \
    for (int t = 0; t < KT; ++t) {                                               \
        if (t == KT - 1) { asm volatile("s_waitcnt vmcnt(0) lgkmcnt(0)" ::: "memory"); } \
        else             { asm volatile("s_waitcnt vmcnt(4) lgkmcnt(0)" ::: "memory"); } \
        __builtin_amdgcn_s_barrier();                                            \
        if (t + 2 < KT) {                                                        \
            const int ko = (t + 2) * SUBT;                                       \
            gl_lds16(gA0 + ko, &Af[nxt][w  ][0][0]);                             \
            gl_lds16(gA1 + ko, &Af[nxt][w+4][0][0]);                             \
            gl_lds16(gB0 + ko, &Bf[nxt][w  ][0][0]);                             \
            gl_lds16(gB1 + ko, &Bf[nxt][w+4][0][0]);                             \
        }                                                                        \
        short8 af[4], bf[4];                                                     \
        _Pragma("unroll")                                                        \
        for (int m = 0; m < 4; ++m)                                              \
            af[m] = *(const short8*)&Af[cur][wr*4 + m][l][0];                    \
        _Pragma("unroll")                                                        \
        for (int n = 0; n < 4; ++n)                                              \
            bf[n] = *(const short8*)&Bf[cur][wc*4 + n][l][0];                    \
        _Pragma("unroll")                                                        \
        for (int m = 0; m < 4; ++m)                                              \
            _Pragma("unroll")                                                    \
            for (int n = 0; n < 4; ++n)                                          \
                acc[m][n] = __builtin_amdgcn_mfma_f32_16x16x32_bf16(bf[n], af[m], acc[m][n], 0, 0, 0); \
        cur = (cur == 2) ? 0 : cur + 1;                                          \
        nxt = (nxt == 2) ? 0 : nxt + 1;                                          \
    }

// =============== Kernel 1: QKV projection (BM=BN=128) ======================
__global__ __launch_bounds__(256)
void qkv_gemm_mfma(const uint16_t* __restrict__ xb, const uint16_t* __restrict__ wq,
                   uint16_t* __restrict__ qkv)
{
    __shared__ ushort Af[3][8][64][8];   // 24 KB
    __shared__ ushort Bf[3][8][64][8];   // 24 KB
    const int t = threadIdx.x;
    const int w = t >> 6, l = t & 63;
    const int wr = w >> 1, wc = w & 1;
    const int lm = l & 15, lk = l >> 4;

    // grid 4410, chunked-XCD swizzle (q=551, r=2)
    const int bid = blockIdx.x;
    const int xcd = bid & 7;
    const int wg = (xcd < 2 ? xcd * 552 : 1104 + (xcd - 2) * 551) + (bid >> 3);
    const int mtile = wg / 18, ctile = wg - mtile * 18;
    const int m0 = mtile * 128, c0 = ctile * 128;

    const uint16_t* gA0 = xb + ((size_t)(mtile*8 + w    ) * KT * 64 + l) * 8;
    const uint16_t* gA1 = xb + ((size_t)(mtile*8 + w + 4) * KT * 64 + l) * 8;
    const uint16_t* gB0 = wq + ((size_t)(ctile*8 + w    ) * KT * 64 + l) * 8;
    const uint16_t* gB1 = wq + ((size_t)(ctile*8 + w + 4) * KT * 64 + l) * 8;

    f32x4 acc[4][4];
    #pragma unroll
    for (int m = 0; m < 4; ++m)
        #pragma unroll
        for (int n = 0; n < 4; ++n) acc[m][n] = (f32x4){0.f,0.f,0.f,0.f};

    GEMM_LOOP

    int sArr[4], hArr[4], dArr[4];
    #pragma unroll
    for (int n = 0; n < 4; ++n) {
        int c = c0 + wc*64 + n*16 + lk*4;
        int s = c / CDIM; int rem = c - s * CDIM;
        sArr[n] = s; hArr[n] = rem >> 6; dArr[n] = rem & 63;
    }
    #pragma unroll
    for (int m = 0; m < 4; ++m) {
        int gm  = m0 + wr*64 + m*16 + lm;
        int b   = gm / NTOK;
        int tok = gm - b * NTOK;
        #pragma unroll
        for (int n = 0; n < 4; ++n) {
            ushort2 u0 = pk2bf(acc[m][n][0], acc[m][n][1]);
            ushort2 u1 = pk2bf(acc[m][n][2], acc[m][n][3]);
            uint2 pk;
            pk.x = (uint32_t)u0.x | ((uint32_t)u0.y << 16);
            pk.y = (uint32_t)u1.x | ((uint32_t)u1.y << 16);
            size_t addr = ((((size_t)b*3 + sArr[n])*HEADS + hArr[n])*NTOK + tok)*DHEAD + dArr[n];
            *(uint2*)(qkv + addr) = pk;
        }
    }
}

// =============== Kernel 2: MFMA flash attention per (b,h) ==================
// Single-stage K/V (89 KB LDS, 1 block/CU, 8 independent waves after stage).
// Fixed-reference softmax in exp2 domain; pads (bias=-43281) underflow to 0.
__global__ __launch_bounds__(512)
void attn_mfma(const uint16_t* __restrict__ qkv, const uint16_t* __restrict__ bias_t,
               uint16_t* __restrict__ o_t)
{
    __shared__ ushort Ks[256][72];    // 36864 B
    __shared__ ushort Vt[64][264];    // 33792 B
    __shared__ ushort Ps[8][16][72];  // 18432 B
    const int bh = blockIdx.x;
    const int b = bh / HEADS, h = bh % HEADS;
    const int t = threadIdx.x;
    const int w = t >> 6, l = t & 63;
    const int lm = l & 15, lk = l >> 4;
    const int wq0 = w * 32;

    const uint16_t* qbase = qkv + (((size_t)b*3 + 0)*HEADS + h) * (NTOK*DHEAD);
    const uint16_t* kbase = qkv + (((size_t)b*3 + 1)*HEADS + h) * (NTOK*DHEAD);
    const uint16_t* vbase = qkv + (((size_t)b*3 + 2)*HEADS + h) * (NTOK*DHEAD);
    const uint16_t* btab  = bias_t + (size_t)h * 256 * 256;

    // ---- stage K (rows >= 245 zeroed) ----
    {
        const int col = (t & 7) * 8;
        #pragma unroll
        for (int p = 0; p < 4; ++p) {
            int row = p * 64 + (t >> 3);
            uint4 val = make_uint4(0u,0u,0u,0u);
            if (row < NTOK) val = *(const uint4*)(kbase + (size_t)row * DHEAD + col);
            *(uint4*)&Ks[row][col] = val;
        }
    }
    // ---- stage V row-major -> transposed Vt[d][j] (one-time) ----
    {
        const int j  = t >> 1;
        const int dh = (t & 1) * 32;
        uint4 r0 = make_uint4(0,0,0,0), r1 = r0, r2 = r0, r3 = r0;
        if (j < NTOK) {
            const uint16_t* src = vbase + (size_t)j * DHEAD + dh;
            r0 = *(const uint4*)(src);
            r1 = *(const uint4*)(src + 8);
            r2 = *(const uint4*)(src + 16);
            r3 = *(const uint4*)(src + 24);
        }
        union { uint4 v[4]; ushort s[32]; } u;
        u.v[0] = r0; u.v[1] = r1; u.v[2] = r2; u.v[3] = r3;
        #pragma unroll
        for (int i = 0; i < 32; ++i)
            Vt[dh + i][j] = u.s[i];
    }

    short8 qf[2][2];
    #pragma unroll
    for (int m = 0; m < 2; ++m) {
        int qrow = wq0 + m*16 + lm; if (qrow > NTOK-1) qrow = NTOK-1;
        #pragma unroll
        for (int k2 = 0; k2 < 2; ++k2)
            qf[m][k2] = *(const short8*)(qbase + (size_t)qrow * DHEAD + k2*32 + lk*8);
    }

    f32x4 acc_o[2][4];
    float lsum[2][4];
    #pragma unroll
    for (int m = 0; m < 2; ++m) {
        #pragma unroll
        for (int n = 0; n < 4; ++n) acc_o[m][n] = (f32x4){0.f,0.f,0.f,0.f};
        #pragma unroll
        for (int r = 0; r < 4; ++r) lsum[m][r] = 0.f;
    }

    __syncthreads();

    for (int jb = 0; jb < 4; ++jb) {
        short8 kf[4][2], vf[4][2];
        #pragma unroll
        for (int n = 0; n < 4; ++n)
            #pragma unroll
            for (int k2 = 0; k2 < 2; ++k2) {
                kf[n][k2] = *(const short8*)&Ks[jb*64 + n*16 + lm][k2*32 + lk*8];
                vf[n][k2] = *(const short8*)&Vt[n*16 + lm][jb*64 + k2*32 + lk*8];
            }

        #pragma unroll
        for (int m = 0; m < 2; ++m) {
            f32x4 sv[4];
            __builtin_amdgcn_s_setprio(1);
            #pragma unroll
            for (int n = 0; n < 4; ++n) {
                f32x4 z = (f32x4){0.f,0.f,0.f,0.f};
                sv[n] = __builtin_amdgcn_mfma_f32_16x16x32_bf16(qf[m][0], kf[n][0], z, 0, 0, 0);
                sv[n] = __builtin_amdgcn_mfma_f32_16x16x32_bf16(qf[m][1], kf[n][1], sv[n], 0, 0, 0);
            }
            __builtin_amdgcn_s_setprio(0);
            #pragma unroll
            for (int n = 0; n < 4; ++n) {
                uint2 bb = *(const uint2*)(btab + (size_t)(jb*64 + n*16 + lm) * 256 + wq0 + m*16 + lk*4);
                float s0 = fmaf(sv[n][0], SCL, bf2f(bb.x & 0xffffu));
                float s1 = fmaf(sv[n][1], SCL, bf2f(bb.x >> 16));
                float s2 = fmaf(sv[n][2], SCL, bf2f(bb.y & 0xffffu));
                float s3 = fmaf(sv[n][3], SCL, bf2f(bb.y >> 16));
                sv[n][0] = exp2f(fminf(s0, PCLAMP));
                sv[n][1] = exp2f(fminf(s1, PCLAMP));
                sv[n][2] = exp2f(fminf(s2, PCLAMP));
                sv[n][3] = exp2f(fminf(s3, PCLAMP));
            }
            #pragma unroll
            for (int n = 0; n < 4; ++n)
                #pragma unroll
                for (int r = 0; r < 4; ++r) {
                    ushort u = pk2bf(sv[n][r], sv[n][r]).x;   // 1-op cvt
                    lsum[m][r] += bf2f(u);                    // rounded-p denominator
                    Ps[w][lk*4 + r][n*16 + lm] = u;
                }
            short8 pf[2];
            #pragma unroll
            for (int k2 = 0; k2 < 2; ++k2)
                pf[k2] = *(const short8*)&Ps[w][lm][k2*32 + lk*8];
            __builtin_amdgcn_s_setprio(1);
            #pragma unroll
            for (int n = 0; n < 4; ++n) {
                acc_o[m][n] = __builtin_amdgcn_mfma_f32_16x16x32_bf16(pf[0], vf[n][0], acc_o[m][n], 0, 0, 0);
                acc_o[m][n] = __builtin_amdgcn_mfma_f32_16x16x32_bf16(pf[1], vf[n][1], acc_o[m][n], 0, 0, 0);
            }
            __builtin_amdgcn_s_setprio(0);
        }
    }

    // epilogue: one cross-lane sum reduce per row, O /= l, tiled store
    #pragma unroll
    for (int m = 0; m < 2; ++m) {
        float inv[4];
        #pragma unroll
        for (int r = 0; r < 4; ++r) {
            float s = lsum[m][r];
            s += __shfl_xor(s, 1);
            s += __shfl_xor(s, 2);
            s += __shfl_xor(s, 4);
            s += __shfl_xor(s, 8);
            inv[r] = 1.f / s;
        }
        #pragma unroll
        for (int r = 0; r < 4; ++r) {
            int q = wq0 + m*16 + lk*4 + r;
            if (q < NTOK) {
                int gm = b * NTOK + q;
                #pragma unroll
                for (int n = 0; n < 4; ++n) {
                    int k = h * DHEAD + n*16 + lm;
                    o_t[tiled_addr(gm, k)] = (uint16_t)f2bf(acc_o[m][n][r] * inv[r]);
                }
            }
        }
    }
}

// =============== Kernel 3: output projection (BM=BN=128) ===================
__global__ __launch_bounds__(256)
void proj_gemm_mfma(const uint16_t* __restrict__ ot, const uint16_t* __restrict__ wp,
                    const float* __restrict__ bias, float* __restrict__ out)
{
    __shared__ ushort Af[3][8][64][8];
    __shared__ ushort Bf[3][8][64][8];
    const int t = threadIdx.x;
    const int w = t >> 6, l = t & 63;
    const int wr = w >> 1, wc = w & 1;
    const int lm = l & 15, lk = l >> 4;

    // grid 1470, chunked-XCD swizzle (q=183, r=6)
    const int bid = blockIdx.x;
    const int xcd = bid & 7;
    const int wg = (xcd < 6 ? xcd * 184 : 1104 + (xcd - 6) * 183) + (bid >> 3);
    const int mtile = wg / 6, ctile = wg - mtile * 6;
    const int m0 = mtile * 128, c0 = ctile * 128;

    const uint16_t* gA0 = ot + ((size_t)(mtile*8 + w    ) * KT * 64 + l) * 8;
    const uint16_t* gA1 = ot + ((size_t)(mtile*8 + w + 4) * KT * 64 + l) * 8;
    const uint16_t* gB0 = wp + ((size_t)(ctile*8 + w    ) * KT * 64 + l) * 8;
    const uint16_t* gB1 = wp + ((size_t)(ctile*8 + w + 4) * KT * 64 + l) * 8;

    f32x4 acc[4][4];
    #pragma unroll
    for (int m = 0; m < 4; ++m)
        #pragma unroll
        for (int n = 0; n < 4; ++n) acc[m][n] = (f32x4){0.f,0.f,0.f,0.f};

    GEMM_LOOP

    float4 bsv[4]; int cArr[4];
    #pragma unroll
    for (int n = 0; n < 4; ++n) {
        cArr[n] = c0 + wc*64 + n*16 + lk*4;
        bsv[n]  = *(const float4*)(bias + cArr[n]);
    }
    #pragma unroll
    for (int m = 0; m < 4; ++m) {
        int gm = m0 + wr*64 + m*16 + lm;
        #pragma unroll
        for (int n = 0; n < 4; ++n) {
            float4 r;
            r.x = acc[m][n][0] + bsv[n].x;
            r.y = acc[m][n][1] + bsv[n].y;
            r.z = acc[m][n][2] + bsv[n].z;
            r.w = acc[m][n][3] + bsv[n].w;
            *(float4*)(out + (size_t)gm * CDIM + cArr[n]) = r;
        }
    }
}

extern "C" void kernel_launch(void* const* d_in, const int* in_sizes, int n_in,
                              void* d_out, int out_size, void* d_ws, size_t ws_size,
                              hipStream_t stream)
{
    (void)n_in; (void)out_size;
    const float* x          = (const float*)d_in[0];
    const float* qkv_w      = (const float*)d_in[1];
    const float* proj_w     = (const float*)d_in[2];
    const float* proj_b     = (const float*)d_in[3];
    const float* bias_table = (const float*)d_in[4];
    const int*   rel        = (const int*)d_in[5];
    const int n_bias = in_sizes[4] / HEADS;

    const size_t qkv_elems = (size_t)BATCH * 3 * HEADS * NTOK * DHEAD;  // 72,253,440
    const size_t o_elems   = (size_t)BATCH * HEADS * NTOK * DHEAD;      // 24,084,480 (= x elems)
    const size_t bt_elems  = (size_t)HEADS * 256 * 256;                 //    786,432
    const size_t wq_elems  = (size_t)3 * CDIM * CDIM;                   //  1,769,472
    const size_t wp_elems  = (size_t)CDIM * CDIM;                       //    589,824

    uint16_t* qkv_ws = (uint16_t*)d_ws;
    uint16_t* o_ws   = qkv_ws + qkv_elems;   // x_tiled until attn overwrites with O_tiled
    uint16_t* bt_ws  = o_ws + o_elems;
    uint16_t* wq_ws  = bt_ws + bt_elems;
    uint16_t* wp_ws  = wq_ws + wq_elems;
    const size_t need = (qkv_elems + o_elems + bt_elems + wq_elems + wp_elems) * sizeof(uint16_t);
    if (ws_size < need) return;   // ~199 MB

    uint16_t* xb = o_ws;

    cvt_all<<<2048, 256, 0, stream>>>(x, qkv_w, proj_w, xb, wq_ws, wp_ws);

    bias_pre<<<dim3(HEADS, 256), 256, 0, stream>>>(bias_table, rel, n_bias, bt_ws);

    qkv_gemm_mfma<<<4410, 256, 0, stream>>>(xb, wq_ws, qkv_ws);

    attn_mfma<<<dim3(BATCH * HEADS), 512, 0, stream>>>(qkv_ws, bt_ws, o_ws);

    proj_gemm_mfma<<<1470, 256, 0, stream>>>(o_ws, wp_ws, proj_b, (float*)d_out);
}

// Round 19
// 321.432 us; speedup vs baseline: 1.0312x; 1.0002x over previous
//
#include <hip/hip_runtime.h>
#include <hip/hip_bf16.h>
#include <stdint.h>
#include <math.h>

#define BATCH 128
#define NTOK 245
#define HEADS 12
#define DHEAD 64
#define CDIM 768
#define KT 24          // CDIM/32 k-tiles
#define SUBT 512       // ushorts per (rowtile,ktile) subtile = 64 slots * 8
#define SCL 0.18033688f      // 0.125 * log2(e)
#define PCLAMP 43.3f         // 30 * log2(e)

typedef __attribute__((ext_vector_type(8))) short short8;
typedef __attribute__((ext_vector_type(4))) float f32x4;

__device__ __forceinline__ float bf2f(uint32_t hbits) {
    union { uint32_t u; float f; } v; v.u = hbits << 16; return v.f;
}
__device__ __forceinline__ uint32_t f2bf(float f) {
    union { float f; uint32_t u; } v; v.f = f;
    return (v.u + 0x7fffu + ((v.u >> 16) & 1u)) >> 16;
}
__device__ __forceinline__ ushort2 pk2bf(float x, float y) {
    union { __hip_bfloat162 h; ushort2 u; } c;
    c.h = __float22bfloat162_rn(make_float2(x, y));
    return c.u;
}
// fragment-tiled global address for element (row m, col k) of a [R][768] matrix
__device__ __forceinline__ size_t tiled_addr(int m, int k) {
    return (((size_t)(m >> 4) * KT + (k >> 5)) * 64 + ((k >> 3) & 3) * 16 + (m & 15)) * 8
           + (k & 7);
}
// async global->LDS, 16B/lane; LDS dest wave-uniform, global src per-lane.
__device__ __forceinline__ void gl_lds16(const uint16_t* g, ushort* lds) {
    __builtin_amdgcn_global_load_lds(
        (const __attribute__((address_space(1))) void*)g,
        (__attribute__((address_space(3))) void*)lds,
        16, 0, 0);
}

// =============== Kernel A: fused fp32->bf16 convert + fragment-tile repack =
#define N8_X  3010560   // 24,084,480 / 8
#define N8_WQ  221184   //  1,769,472 / 8
#define N8_WP   73728   //    589,824 / 8
__global__ __launch_bounds__(256)
void cvt_all(const float* __restrict__ x, const float* __restrict__ wq,
             const float* __restrict__ wp, uint16_t* __restrict__ xd,
             uint16_t* __restrict__ wqd, uint16_t* __restrict__ wpd)
{
    int i = blockIdx.x * 256 + threadIdx.x;
    const int stride = gridDim.x * 256;
    const int total = N8_X + N8_WQ + N8_WP;
    for (; i < total; i += stride) {
        const float* src; uint16_t* dst; int j;
        if (i < N8_X)              { src = x;  dst = xd;  j = i; }
        else if (i < N8_X + N8_WQ) { src = wq; dst = wqd; j = i - N8_X; }
        else                       { src = wp; dst = wpd; j = i - N8_X - N8_WQ; }
        const int sl = j & 63;
        const int tile = j >> 6;
        const int rt = tile / KT, kt = tile - rt * KT;
        const size_t soff = (size_t)(rt * 16 + (sl & 15)) * CDIM + kt * 32 + (sl >> 4) * 8;
        float4 a = *(const float4*)(src + soff);
        float4 b = *(const float4*)(src + soff + 4);
        ushort2 p0 = pk2bf(a.x, a.y), p1 = pk2bf(a.z, a.w);
        ushort2 p2 = pk2bf(b.x, b.y), p3 = pk2bf(b.z, b.w);
        uint4 o;
        o.x = (uint32_t)p0.x | ((uint32_t)p0.y << 16);
        o.y = (uint32_t)p1.x | ((uint32_t)p1.y << 16);
        o.z = (uint32_t)p2.x | ((uint32_t)p2.y << 16);
        o.w = (uint32_t)p3.x | ((uint32_t)p3.y << 16);
        *(uint4*)(dst + (size_t)j * 8) = o;
    }
}

// =============== Kernel 0: bias precompute (pre-scaled by log2 e) ==========
__global__ __launch_bounds__(256)
void bias_pre(const float* __restrict__ bias_table, const int* __restrict__ rel,
              int n_bias, uint16_t* __restrict__ bias_t)
{
    const int h = blockIdx.x, j = blockIdx.y, q = threadIdx.x;
    float v = -43281.f;   // -30000 * log2(e): pad -> exp2 underflows to 0
    if (j < NTOK && q < NTOK)
        v = bias_table[(size_t)h * n_bias + rel[q * NTOK + j]] * 1.44269504f;
    bias_t[((size_t)h * 256 + j) * 256 + q] = (uint16_t)f2bf(v);
}

// =============== GEMM core loop (3-buf rotation, counted vmcnt) ============
#define GEMM_LOOP                                                                \
    gl_lds16(gA0, &Af[0][w  ][0][0]);                                            \
    gl_lds16(gA1, &Af[0][w+4][0][0]);                                            \
    gl_lds16(gB0, &Bf[0][w  ][0][0]);                                            \
    gl_lds16(gB1, &Bf[0][w+4][0][0]);                                            \
    gl_lds16(gA0 + SUBT, &Af[1][w  ][0][0]);                                     \
    gl_lds16(gA1 + SUBT, &Af[1][w+4][0][0]);                                     \
    gl_lds16(gB0 + SUBT, &Bf[1][w  ][0][0]);                                     \
    gl_lds16(gB1 + SUBT, &Bf[1][w+4][0][0]);                                     \
    int cur = 0, nxt = 2;                                                        \
    _Pragma("unroll 1")                                                          \
    for (int t = 0; t < KT; ++t) {                                               \
        if (t == KT - 1) { asm volatile("s_waitcnt vmcnt(0) lgkmcnt(0)" ::: "memory"); } \
        else             { asm volatile("s_waitcnt vmcnt(4) lgkmcnt(0)" ::: "memory"); } \
        __builtin_amdgcn_s_barrier();                                            \
        if (t + 2 < KT) {                                                        \
            const int ko = (t + 2) * SUBT;                                       \
            gl_lds16(gA0 + ko, &Af[nxt][w  ][0][0]);                             \
            gl_lds16(gA1 + ko, &Af[nxt][w+4][0][0]);                             \
            gl_lds16(gB0 + ko, &Bf[nxt][w  ][0][0]);                             \
            gl_lds16(gB1 + ko, &Bf[nxt][w+4][0][0]);                             \
        }                                                                        \
        short8 af[4], bf[4];                                                     \
        _Pragma("unroll")                                                        \
        for (int m = 0; m < 4; ++m)                                              \
            af[m] = *(const short8*)&Af[cur][wr*4 + m][l][0];                    \
        _Pragma("unroll")                                                        \
        for (int n = 0; n < 4; ++n)                                              \
            bf[n] = *(const short8*)&Bf[cur][wc*4 + n][l][0];                    \
        _Pragma("unroll")                                                        \
        for (int m = 0; m < 4; ++m)                                              \
            _Pragma("unroll")                                                    \
            for (int n = 0; n < 4; ++n)                                          \
                acc[m][n] = __builtin_amdgcn_mfma_f32_16x16x32_bf16(bf[n], af[m], acc[m][n], 0, 0, 0); \
        cur = (cur == 2) ? 0 : cur + 1;                                          \
        nxt = (nxt == 2) ? 0 : nxt + 1;                                          \
    }

// =============== Kernel 1: QKV projection (BM=BN=128) ======================
__global__ __launch_bounds__(256)
void qkv_gemm_mfma(const uint16_t* __restrict__ xb, const uint16_t* __restrict__ wq,
                   uint16_t* __restrict__ qkv)
{
    __shared__ ushort Af[3][8][64][8];   // 24 KB
    __shared__ ushort Bf[3][8][64][8];   // 24 KB
    const int t = threadIdx.x;
    const int w = t >> 6, l = t & 63;
    const int wr = w >> 1, wc = w & 1;
    const int lm = l & 15, lk = l >> 4;

    // grid 4410, chunked-XCD swizzle (q=551, r=2)
    const int bid = blockIdx.x;
    const int xcd = bid & 7;
    const int wg = (xcd < 2 ? xcd * 552 : 1104 + (xcd - 2) * 551) + (bid >> 3);
    const int mtile = wg / 18, ctile = wg - mtile * 18;
    const int m0 = mtile * 128, c0 = ctile * 128;

    const uint16_t* gA0 = xb + ((size_t)(mtile*8 + w    ) * KT * 64 + l) * 8;
    const uint16_t* gA1 = xb + ((size_t)(mtile*8 + w + 4) * KT * 64 + l) * 8;
    const uint16_t* gB0 = wq + ((size_t)(ctile*8 + w    ) * KT * 64 + l) * 8;
    const uint16_t* gB1 = wq + ((size_t)(ctile*8 + w + 4) * KT * 64 + l) * 8;

    f32x4 acc[4][4];
    #pragma unroll
    for (int m = 0; m < 4; ++m)
        #pragma unroll
        for (int n = 0; n < 4; ++n) acc[m][n] = (f32x4){0.f,0.f,0.f,0.f};

    GEMM_LOOP

    int sArr[4], hArr[4], dArr[4];
    #pragma unroll
    for (int n = 0; n < 4; ++n) {
        int c = c0 + wc*64 + n*16 + lk*4;
        int s = c / CDIM; int rem = c - s * CDIM;
        sArr[n] = s; hArr[n] = rem >> 6; dArr[n] = rem & 63;
    }
    #pragma unroll
    for (int m = 0; m < 4; ++m) {
        int gm  = m0 + wr*64 + m*16 + lm;
        int b   = gm / NTOK;
        int tok = gm - b * NTOK;
        #pragma unroll
        for (int n = 0; n < 4; ++n) {
            ushort2 u0 = pk2bf(acc[m][n][0], acc[m][n][1]);
            ushort2 u1 = pk2bf(acc[m][n][2], acc[m][n][3]);
            uint2 pk;
            pk.x = (uint32_t)u0.x | ((uint32_t)u0.y << 16);
            pk.y = (uint32_t)u1.x | ((uint32_t)u1.y << 16);
            size_t addr = ((((size_t)b*3 + sArr[n])*HEADS + hArr[n])*NTOK + tok)*DHEAD + dArr[n];
            *(uint2*)(qkv + addr) = pk;
        }
    }
}

// =============== Kernel 2: MFMA flash attention per (b,h) ==================
// Single-stage K/V (89 KB LDS). Fixed-reference softmax in exp2 domain;
// pads (bias=-43281) underflow to 0. Bias prefetched one jb ahead (T14).
__global__ __launch_bounds__(512)
void attn_mfma(const uint16_t* __restrict__ qkv, const uint16_t* __restrict__ bias_t,
               uint16_t* __restrict__ o_t)
{
    __shared__ ushort Ks[256][72];    // 36864 B
    __shared__ ushort Vt[64][264];    // 33792 B
    __shared__ ushort Ps[8][16][72];  // 18432 B
    const int bh = blockIdx.x;
    const int b = bh / HEADS, h = bh % HEADS;
    const int t = threadIdx.x;
    const int w = t >> 6, l = t & 63;
    const int lm = l & 15, lk = l >> 4;
    const int wq0 = w * 32;

    const uint16_t* qbase = qkv + (((size_t)b*3 + 0)*HEADS + h) * (NTOK*DHEAD);
    const uint16_t* kbase = qkv + (((size_t)b*3 + 1)*HEADS + h) * (NTOK*DHEAD);
    const uint16_t* vbase = qkv + (((size_t)b*3 + 2)*HEADS + h) * (NTOK*DHEAD);
    const uint16_t* btab  = bias_t + (size_t)h * 256 * 256;

    // ---- stage K (rows >= 245 zeroed) ----
    {
        const int col = (t & 7) * 8;
        #pragma unroll
        for (int p = 0; p < 4; ++p) {
            int row = p * 64 + (t >> 3);
            uint4 val = make_uint4(0u,0u,0u,0u);
            if (row < NTOK) val = *(const uint4*)(kbase + (size_t)row * DHEAD + col);
            *(uint4*)&Ks[row][col] = val;
        }
    }
    // ---- stage V row-major -> transposed Vt[d][j] (one-time) ----
    {
        const int j  = t >> 1;
        const int dh = (t & 1) * 32;
        uint4 r0 = make_uint4(0,0,0,0), r1 = r0, r2 = r0, r3 = r0;
        if (j < NTOK) {
            const uint16_t* src = vbase + (size_t)j * DHEAD + dh;
            r0 = *(const uint4*)(src);
            r1 = *(const uint4*)(src + 8);
            r2 = *(const uint4*)(src + 16);
            r3 = *(const uint4*)(src + 24);
        }
        union { uint4 v[4]; ushort s[32]; } u;
        u.v[0] = r0; u.v[1] = r1; u.v[2] = r2; u.v[3] = r3;
        #pragma unroll
        for (int i = 0; i < 32; ++i)
            Vt[dh + i][j] = u.s[i];
    }

    short8 qf[2][2];
    #pragma unroll
    for (int m = 0; m < 2; ++m) {
        int qrow = wq0 + m*16 + lm; if (qrow > NTOK-1) qrow = NTOK-1;
        #pragma unroll
        for (int k2 = 0; k2 < 2; ++k2)
            qf[m][k2] = *(const short8*)(qbase + (size_t)qrow * DHEAD + k2*32 + lk*8);
    }

    f32x4 acc_o[2][4];
    float lsum[2][4];
    #pragma unroll
    for (int m = 0; m < 2; ++m) {
        #pragma unroll
        for (int n = 0; n < 4; ++n) acc_o[m][n] = (f32x4){0.f,0.f,0.f,0.f};
        #pragma unroll
        for (int r = 0; r < 4; ++r) lsum[m][r] = 0.f;
    }

    // bias prefetch for jb=0 (registers; hidden under K/V staging wait)
    uint2 bb_c[2][4];
    #pragma unroll
    for (int m = 0; m < 2; ++m)
        #pragma unroll
        for (int n = 0; n < 4; ++n)
            bb_c[m][n] = *(const uint2*)(btab + (size_t)(n*16 + lm) * 256 + wq0 + m*16 + lk*4);

    __syncthreads();

    for (int jb = 0; jb < 4; ++jb) {
        short8 kf[4][2], vf[4][2];
        #pragma unroll
        for (int n = 0; n < 4; ++n)
            #pragma unroll
            for (int k2 = 0; k2 < 2; ++k2) {
                kf[n][k2] = *(const short8*)&Ks[jb*64 + n*16 + lm][k2*32 + lk*8];
                vf[n][k2] = *(const short8*)&Vt[n*16 + lm][jb*64 + k2*32 + lk*8];
            }
        // prefetch next jb's bias while this jb computes
        uint2 bb_n[2][4];
        if (jb < 3) {
            #pragma unroll
            for (int m = 0; m < 2; ++m)
                #pragma unroll
                for (int n = 0; n < 4; ++n)
                    bb_n[m][n] = *(const uint2*)(btab + (size_t)((jb+1)*64 + n*16 + lm) * 256 + wq0 + m*16 + lk*4);
        }

        #pragma unroll
        for (int m = 0; m < 2; ++m) {
            f32x4 sv[4];
            __builtin_amdgcn_s_setprio(1);
            #pragma unroll
            for (int n = 0; n < 4; ++n) {
                f32x4 z = (f32x4){0.f,0.f,0.f,0.f};
                sv[n] = __builtin_amdgcn_mfma_f32_16x16x32_bf16(qf[m][0], kf[n][0], z, 0, 0, 0);
                sv[n] = __builtin_amdgcn_mfma_f32_16x16x32_bf16(qf[m][1], kf[n][1], sv[n], 0, 0, 0);
            }
            __builtin_amdgcn_s_setprio(0);
            #pragma unroll
            for (int n = 0; n < 4; ++n) {
                uint2 bb = bb_c[m][n];
                float s0 = fmaf(sv[n][0], SCL, bf2f(bb.x & 0xffffu));
                float s1 = fmaf(sv[n][1], SCL, bf2f(bb.x >> 16));
                float s2 = fmaf(sv[n][2], SCL, bf2f(bb.y & 0xffffu));
                float s3 = fmaf(sv[n][3], SCL, bf2f(bb.y >> 16));
                sv[n][0] = exp2f(fminf(s0, PCLAMP));
                sv[n][1] = exp2f(fminf(s1, PCLAMP));
                sv[n][2] = exp2f(fminf(s2, PCLAMP));
                sv[n][3] = exp2f(fminf(s3, PCLAMP));
            }
            #pragma unroll
            for (int n = 0; n < 4; ++n)
                #pragma unroll
                for (int r = 0; r < 4; ++r) {
                    ushort u = pk2bf(sv[n][r], sv[n][r]).x;   // 1-op cvt
                    lsum[m][r] += bf2f(u);                    // rounded-p denominator
                    Ps[w][lk*4 + r][n*16 + lm] = u;
                }
            short8 pf[2];
            #pragma unroll
            for (int k2 = 0; k2 < 2; ++k2)
                pf[k2] = *(const short8*)&Ps[w][lm][k2*32 + lk*8];
            __builtin_amdgcn_s_setprio(1);
            #pragma unroll
            for (int n = 0; n < 4; ++n) {
                acc_o[m][n] = __builtin_amdgcn_mfma_f32_16x16x32_bf16(pf[0], vf[n][0], acc_o[m][n], 0, 0, 0);
                acc_o[m][n] = __builtin_amdgcn_mfma_f32_16x16x32_bf16(pf[1], vf[n][1], acc_o[m][n], 0, 0, 0);
            }
            __builtin_amdgcn_s_setprio(0);
        }
        if (jb < 3) {
            #pragma unroll
            for (int m = 0; m < 2; ++m)
                #pragma unroll
                for (int n = 0; n < 4; ++n)
                    bb_c[m][n] = bb_n[m][n];
        }
    }

    // epilogue: one cross-lane sum reduce per row, O /= l, tiled store
    #pragma unroll
    for (int m = 0; m < 2; ++m) {
        float inv[4];
        #pragma unroll
        for (int r = 0; r < 4; ++r) {
            float s = lsum[m][r];
            s += __shfl_xor(s, 1);
            s += __shfl_xor(s, 2);
            s += __shfl_xor(s, 4);
            s += __shfl_xor(s, 8);
            inv[r] = 1.f / s;
        }
        #pragma unroll
        for (int r = 0; r < 4; ++r) {
            int q = wq0 + m*16 + lk*4 + r;
            if (q < NTOK) {
                int gm = b * NTOK + q;
                #pragma unroll
                for (int n = 0; n < 4; ++n) {
                    int k = h * DHEAD + n*16 + lm;
                    o_t[tiled_addr(gm, k)] = (uint16_t)f2bf(acc_o[m][n][r] * inv[r]);
                }
            }
        }
    }
}

// =============== Kernel 3: output projection (BM=BN=128) ===================
__global__ __launch_bounds__(256)
void proj_gemm_mfma(const uint16_t* __restrict__ ot, const uint16_t* __restrict__ wp,
                    const float* __restrict__ bias, float* __restrict__ out)
{
    __shared__ ushort Af[3][8][64][8];
    __shared__ ushort Bf[3][8][64][8];
    const int t = threadIdx.x;
    const int w = t >> 6, l = t & 63;
    const int wr = w >> 1, wc = w & 1;
    const int lm = l & 15, lk = l >> 4;

    // grid 1470, chunked-XCD swizzle (q=183, r=6)
    const int bid = blockIdx.x;
    const int xcd = bid & 7;
    const int wg = (xcd < 6 ? xcd * 184 : 1104 + (xcd - 6) * 183) + (bid >> 3);
    const int mtile = wg / 6, ctile = wg - mtile * 6;
    const int m0 = mtile * 128, c0 = ctile * 128;

    const uint16_t* gA0 = ot + ((size_t)(mtile*8 + w    ) * KT * 64 + l) * 8;
    const uint16_t* gA1 = ot + ((size_t)(mtile*8 + w + 4) * KT * 64 + l) * 8;
    const uint16_t* gB0 = wp + ((size_t)(ctile*8 + w    ) * KT * 64 + l) * 8;
    const uint16_t* gB1 = wp + ((size_t)(ctile*8 + w + 4) * KT * 64 + l) * 8;

    f32x4 acc[4][4];
    #pragma unroll
    for (int m = 0; m < 4; ++m)
        #pragma unroll
        for (int n = 0; n < 4; ++n) acc[m][n] = (f32x4){0.f,0.f,0.f,0.f};

    GEMM_LOOP

    float4 bsv[4]; int cArr[4];
    #pragma unroll
    for (int n = 0; n < 4; ++n) {
        cArr[n] = c0 + wc*64 + n*16 + lk*4;
        bsv[n]  = *(const float4*)(bias + cArr[n]);
    }
    #pragma unroll
    for (int m = 0; m < 4; ++m) {
        int gm = m0 + wr*64 + m*16 + lm;
        #pragma unroll
        for (int n = 0; n < 4; ++n) {
            float4 r;
            r.x = acc[m][n][0] + bsv[n].x;
            r.y = acc[m][n][1] + bsv[n].y;
            r.z = acc[m][n][2] + bsv[n].z;
            r.w = acc[m][n][3] + bsv[n].w;
            *(float4*)(out + (size_t)gm * CDIM + cArr[n]) = r;
        }
    }
}

extern "C" void kernel_launch(void* const* d_in, const int* in_sizes, int n_in,
                              void* d_out, int out_size, void* d_ws, size_t ws_size,
                              hipStream_t stream)
{
    (void)n_in; (void)out_size;
    const float* x          = (const float*)d_in[0];
    const float* qkv_w      = (const float*)d_in[1];
    const float* proj_w     = (const float*)d_in[2];
    const float* proj_b     = (const float*)d_in[3];
    const float* bias_table = (const float*)d_in[4];
    const int*   rel        = (const int*)d_in[5];
    const int n_bias = in_sizes[4] / HEADS;

    const size_t qkv_elems = (size_t)BATCH * 3 * HEADS * NTOK * DHEAD;  // 72,253,440
    const size_t o_elems   = (size_t)BATCH * HEADS * NTOK * DHEAD;      // 24,084,480 (= x elems)
    const size_t bt_elems  = (size_t)HEADS * 256 * 256;                 //    786,432
    const size_t wq_elems  = (size_t)3 * CDIM * CDIM;                   //  1,769,472
    const size_t wp_elems  = (size_t)CDIM * CDIM;                       //    589,824

    uint16_t* qkv_ws = (uint16_t*)d_ws;
    uint16_t* o_ws   = qkv_ws + qkv_elems;   // x_tiled until attn overwrites with O_tiled
    uint16_t* bt_ws  = o_ws + o_elems;
    uint16_t* wq_ws  = bt_ws + bt_elems;
    uint16_t* wp_ws  = wq_ws + wq_elems;
    const size_t need = (qkv_elems + o_elems + bt_elems + wq_elems + wp_elems) * sizeof(uint16_t);
    if (ws_size < need) return;   // ~199 MB

    uint16_t* xb = o_ws;

    cvt_all<<<2048, 256, 0, stream>>>(x, qkv_w, proj_w, xb, wq_ws, wp_ws);

    bias_pre<<<dim3(HEADS, 256), 256, 0, stream>>>(bias_table, rel, n_bias, bt_ws);

    qkv_gemm_mfma<<<4410, 256, 0, stream>>>(xb, wq_ws, qkv_ws);

    attn_mfma<<<dim3(BATCH * HEADS), 512, 0, stream>>>(qkv_ws, bt_ws, o_ws);

    proj_gemm_mfma<<<1470, 256, 0, stream>>>(o_ws, wp_ws, proj_b, (float*)d_out);
}

// Round 20
// 320.625 us; speedup vs baseline: 1.0338x; 1.0025x over previous
//
#include <hip/hip_runtime.h>
#include <hip/hip_bf16.h>
#include <stdint.h>
#include <math.h>

#define BATCH 128
#define NTOK 245
#define HEADS 12
#define DHEAD 64
#define CDIM 768
#define KT 24          // CDIM/32 k-tiles
#define SUBT 512       // ushorts per (rowtile,ktile) subtile = 64 slots * 8
#define SCL 0.18033688f      // 0.125 * log2(e)
#define PCLAMP 43.3f         // 30 * log2(e)

typedef __attribute__((ext_vector_type(8))) short short8;
typedef __attribute__((ext_vector_type(4))) float f32x4;

__device__ __forceinline__ float bf2f(uint32_t hbits) {
    union { uint32_t u; float f; } v; v.u = hbits << 16; return v.f;
}
__device__ __forceinline__ uint32_t f2bf(float f) {
    union { float f; uint32_t u; } v; v.f = f;
    return (v.u + 0x7fffu + ((v.u >> 16) & 1u)) >> 16;
}
__device__ __forceinline__ ushort2 pk2bf(float x, float y) {
    union { __hip_bfloat162 h; ushort2 u; } c;
    c.h = __float22bfloat162_rn(make_float2(x, y));
    return c.u;
}
// fragment-tiled global address for element (row m, col k) of a [R][768] matrix
__device__ __forceinline__ size_t tiled_addr(int m, int k) {
    return (((size_t)(m >> 4) * KT + (k >> 5)) * 64 + ((k >> 3) & 3) * 16 + (m & 15)) * 8
           + (k & 7);
}
// async global->LDS, 16B/lane; LDS dest wave-uniform, global src per-lane.
__device__ __forceinline__ void gl_lds16(const uint16_t* g, ushort* lds) {
    __builtin_amdgcn_global_load_lds(
        (const __attribute__((address_space(1))) void*)g,
        (__attribute__((address_space(3))) void*)lds,
        16, 0, 0);
}

// =============== Kernel A: fused convert/repack + bias gather ==============
// Segments: x, qkv_w, proj_w (fp32 -> bf16, fragment-tiled) and the bias
// table gather (pre-scaled by log2 e). One launch; bias work overlaps the
// BW-bound x conversion.
#define N8_X  3010560   // 24,084,480 / 8
#define N8_WQ  221184   //  1,769,472 / 8
#define N8_WP   73728   //    589,824 / 8
#define N8_CVT (N8_X + N8_WQ + N8_WP)
#define NBIAS_ITEMS (HEADS * 256 * 256)   // 786,432
__global__ __launch_bounds__(256)
void cvt_all(const float* __restrict__ x, const float* __restrict__ wq,
             const float* __restrict__ wp, uint16_t* __restrict__ xd,
             uint16_t* __restrict__ wqd, uint16_t* __restrict__ wpd,
             const float* __restrict__ bias_table, const int* __restrict__ rel,
             int n_bias, uint16_t* __restrict__ bias_t)
{
    int i = blockIdx.x * 256 + threadIdx.x;
    const int stride = gridDim.x * 256;
    const int total = N8_CVT + NBIAS_ITEMS;
    for (; i < total; i += stride) {
        if (i < N8_CVT) {
            const float* src; uint16_t* dst; int j;
            if (i < N8_X)              { src = x;  dst = xd;  j = i; }
            else if (i < N8_X + N8_WQ) { src = wq; dst = wqd; j = i - N8_X; }
            else                       { src = wp; dst = wpd; j = i - N8_X - N8_WQ; }
            const int sl = j & 63;
            const int tile = j >> 6;
            const int rt = tile / KT, kt = tile - rt * KT;
            const size_t soff = (size_t)(rt * 16 + (sl & 15)) * CDIM + kt * 32 + (sl >> 4) * 8;
            float4 a = *(const float4*)(src + soff);
            float4 b = *(const float4*)(src + soff + 4);
            ushort2 p0 = pk2bf(a.x, a.y), p1 = pk2bf(a.z, a.w);
            ushort2 p2 = pk2bf(b.x, b.y), p3 = pk2bf(b.z, b.w);
            uint4 o;
            o.x = (uint32_t)p0.x | ((uint32_t)p0.y << 16);
            o.y = (uint32_t)p1.x | ((uint32_t)p1.y << 16);
            o.z = (uint32_t)p2.x | ((uint32_t)p2.y << 16);
            o.w = (uint32_t)p3.x | ((uint32_t)p3.y << 16);
            *(uint4*)(dst + (size_t)j * 8) = o;
        } else {
            const int j3 = i - N8_CVT;          // h*65536 + j*256 + q
            const int h  = j3 >> 16;
            const int jj = (j3 >> 8) & 255;
            const int q  = j3 & 255;
            float v = -43281.f;   // -30000*log2(e): pad -> exp2 underflows to 0
            if (jj < NTOK && q < NTOK)
                v = bias_table[(size_t)h * n_bias + rel[q * NTOK + jj]] * 1.44269504f;
            bias_t[j3] = (uint16_t)f2bf(v);
        }
    }
}

// =============== GEMM core loop (3-buf rotation, counted vmcnt) ============
// RAW: tile t staged at iter t-2; vmcnt(4) retires the 4 oldest loads.
// WAR: buffer re-staged only after a barrier whose lgkmcnt(0) drained all
//      waves' reads of it.
#define GEMM_LOOP                                                                \
    gl_lds16(gA0, &Af[0][w  ][0][0]);                                            \
    gl_lds16(gA1, &Af[0][w+4][0][0]);                                            \
    gl_lds16(gB0, &Bf[0][w  ][0][0]);                                            \
    gl_lds16(gB1, &Bf[0][w+4][0][0]);                                            \
    gl_lds16(gA0 + SUBT, &Af[1][w  ][0][0]);                                     \
    gl_lds16(gA1 + SUBT, &Af[1][w+4][0][0]);                                     \
    gl_lds16(gB0 + SUBT, &Bf[1][w  ][0][0]);                                     \
    gl_lds16(gB1 + SUBT, &Bf[1][w+4][0][0]);                                     \
    int cur = 0, nxt = 2;                                                        \
    _Pragma("unroll 1")                                                          \
    for (int t = 0; t < KT; ++t) {                                               \
        if (t == KT - 1) { asm volatile("s_waitcnt vmcnt(0) lgkmcnt(0)" ::: "memory"); } \
        else             { asm volatile("s_waitcnt vmcnt(4) lgkmcnt(0)" ::: "memory"); } \
        __builtin_amdgcn_s_barrier();                                            \
        if (t + 2 < KT) {                                                        \
            const int ko = (t + 2) * SUBT;                                       \
            gl_lds16(gA0 + ko, &Af[nxt][w  ][0][0]);                             \
            gl_lds16(gA1 + ko, &Af[nxt][w+4][0][0]);                             \
            gl_lds16(gB0 + ko, &Bf[nxt][w  ][0][0]);                             \
            gl_lds16(gB1 + ko, &Bf[nxt][w+4][0][0]);                             \
        }                                                                        \
        short8 af[4], bf[4];                                                     \
        _Pragma("unroll")                                                        \
        for (int m = 0; m < 4; ++m)                                              \
            af[m] = *(const short8*)&Af[cur][wr*4 + m][l][0];                    \
        _Pragma("unroll")                                                        \
        for (int n = 0; n < 4; ++n)                                              \
            bf[n] = *(const short8*)&Bf[cur][wc*4 + n][l][0];                    \
        _Pragma("unroll")                                                        \
        for (int m = 0; m < 4; ++m)                                              \
            _Pragma("unroll")                                                    \
            for (int n = 0; n < 4; ++n)                                          \
                acc[m][n] = __builtin_amdgcn_mfma_f32_16x16x32_bf16(bf[n], af[m], acc[m][n], 0, 0, 0); \
        cur = (cur == 2) ? 0 : cur + 1;                                          \
        nxt = (nxt == 2) ? 0 : nxt + 1;                                          \
    }

// =============== Kernel 1: QKV projection (BM=BN=128) ======================
__global__ __launch_bounds__(256)
void qkv_gemm_mfma(const uint16_t* __restrict__ xb, const uint16_t* __restrict__ wq,
                   uint16_t* __restrict__ qkv)
{
    __shared__ ushort Af[3][8][64][8];   // 24 KB
    __shared__ ushort Bf[3][8][64][8];   // 24 KB
    const int t = threadIdx.x;
    const int w = t >> 6, l = t & 63;
    const int wr = w >> 1, wc = w & 1;
    const int lm = l & 15, lk = l >> 4;

    // grid 4410, chunked-XCD swizzle (q=551, r=2)
    const int bid = blockIdx.x;
    const int xcd = bid & 7;
    const int wg = (xcd < 2 ? xcd * 552 : 1104 + (xcd - 2) * 551) + (bid >> 3);
    const int mtile = wg / 18, ctile = wg - mtile * 18;
    const int m0 = mtile * 128, c0 = ctile * 128;

    const uint16_t* gA0 = xb + ((size_t)(mtile*8 + w    ) * KT * 64 + l) * 8;
    const uint16_t* gA1 = xb + ((size_t)(mtile*8 + w + 4) * KT * 64 + l) * 8;
    const uint16_t* gB0 = wq + ((size_t)(ctile*8 + w    ) * KT * 64 + l) * 8;
    const uint16_t* gB1 = wq + ((size_t)(ctile*8 + w + 4) * KT * 64 + l) * 8;

    f32x4 acc[4][4];
    #pragma unroll
    for (int m = 0; m < 4; ++m)
        #pragma unroll
        for (int n = 0; n < 4; ++n) acc[m][n] = (f32x4){0.f,0.f,0.f,0.f};

    GEMM_LOOP

    int sArr[4], hArr[4], dArr[4];
    #pragma unroll
    for (int n = 0; n < 4; ++n) {
        int c = c0 + wc*64 + n*16 + lk*4;
        int s = c / CDIM; int rem = c - s * CDIM;
        sArr[n] = s; hArr[n] = rem >> 6; dArr[n] = rem & 63;
    }
    #pragma unroll
    for (int m = 0; m < 4; ++m) {
        int gm  = m0 + wr*64 + m*16 + lm;
        int b   = gm / NTOK;
        int tok = gm - b * NTOK;
        #pragma unroll
        for (int n = 0; n < 4; ++n) {
            ushort2 u0 = pk2bf(acc[m][n][0], acc[m][n][1]);
            ushort2 u1 = pk2bf(acc[m][n][2], acc[m][n][3]);
            uint2 pk;
            pk.x = (uint32_t)u0.x | ((uint32_t)u0.y << 16);
            pk.y = (uint32_t)u1.x | ((uint32_t)u1.y << 16);
            size_t addr = ((((size_t)b*3 + sArr[n])*HEADS + hArr[n])*NTOK + tok)*DHEAD + dArr[n];
            *(uint2*)(qkv + addr) = pk;
        }
    }
}

// =============== Kernel 2: MFMA flash attention per (b,h) ==================
// Single-stage K/V (89 KB LDS). Fixed-reference softmax in exp2 domain;
// pads (bias=-43281) underflow to 0. Bias prefetched one jb ahead (T14).
__global__ __launch_bounds__(512)
void attn_mfma(const uint16_t* __restrict__ qkv, const uint16_t* __restrict__ bias_t,
               uint16_t* __restrict__ o_t)
{
    __shared__ ushort Ks[256][72];    // 36864 B
    __shared__ ushort Vt[64][264];    // 33792 B
    __shared__ ushort Ps[8][16][72];  // 18432 B
    const int bh = blockIdx.x;
    const int b = bh / HEADS, h = bh % HEADS;
    const int t = threadIdx.x;
    const int w = t >> 6, l = t & 63;
    const int lm = l & 15, lk = l >> 4;
    const int wq0 = w * 32;

    const uint16_t* qbase = qkv + (((size_t)b*3 + 0)*HEADS + h) * (NTOK*DHEAD);
    const uint16_t* kbase = qkv + (((size_t)b*3 + 1)*HEADS + h) * (NTOK*DHEAD);
    const uint16_t* vbase = qkv + (((size_t)b*3 + 2)*HEADS + h) * (NTOK*DHEAD);
    const uint16_t* btab  = bias_t + (size_t)h * 256 * 256;

    // ---- stage K (rows >= 245 zeroed) ----
    {
        const int col = (t & 7) * 8;
        #pragma unroll
        for (int p = 0; p < 4; ++p) {
            int row = p * 64 + (t >> 3);
            uint4 val = make_uint4(0u,0u,0u,0u);
            if (row < NTOK) val = *(const uint4*)(kbase + (size_t)row * DHEAD + col);
            *(uint4*)&Ks[row][col] = val;
        }
    }
    // ---- stage V row-major -> transposed Vt[d][j] (one-time) ----
    {
        const int j  = t >> 1;
        const int dh = (t & 1) * 32;
        uint4 r0 = make_uint4(0,0,0,0), r1 = r0, r2 = r0, r3 = r0;
        if (j < NTOK) {
            const uint16_t* src = vbase + (size_t)j * DHEAD + dh;
            r0 = *(const uint4*)(src);
            r1 = *(const uint4*)(src + 8);
            r2 = *(const uint4*)(src + 16);
            r3 = *(const uint4*)(src + 24);
        }
        union { uint4 v[4]; ushort s[32]; } u;
        u.v[0] = r0; u.v[1] = r1; u.v[2] = r2; u.v[3] = r3;
        #pragma unroll
        for (int i = 0; i < 32; ++i)
            Vt[dh + i][j] = u.s[i];
    }

    short8 qf[2][2];
    #pragma unroll
    for (int m = 0; m < 2; ++m) {
        int qrow = wq0 + m*16 + lm; if (qrow > NTOK-1) qrow = NTOK-1;
        #pragma unroll
        for (int k2 = 0; k2 < 2; ++k2)
            qf[m][k2] = *(const short8*)(qbase + (size_t)qrow * DHEAD + k2*32 + lk*8);
    }

    f32x4 acc_o[2][4];
    float lsum[2][4];
    #pragma unroll
    for (int m = 0; m < 2; ++m) {
        #pragma unroll
        for (int n = 0; n < 4; ++n) acc_o[m][n] = (f32x4){0.f,0.f,0.f,0.f};
        #pragma unroll
        for (int r = 0; r < 4; ++r) lsum[m][r] = 0.f;
    }

    // bias prefetch for jb=0 (registers; hidden under K/V staging wait)
    uint2 bb_c[2][4];
    #pragma unroll
    for (int m = 0; m < 2; ++m)
        #pragma unroll
        for (int n = 0; n < 4; ++n)
            bb_c[m][n] = *(const uint2*)(btab + (size_t)(n*16 + lm) * 256 + wq0 + m*16 + lk*4);

    __syncthreads();

    for (int jb = 0; jb < 4; ++jb) {
        short8 kf[4][2], vf[4][2];
        #pragma unroll
        for (int n = 0; n < 4; ++n)
            #pragma unroll
            for (int k2 = 0; k2 < 2; ++k2) {
                kf[n][k2] = *(const short8*)&Ks[jb*64 + n*16 + lm][k2*32 + lk*8];
                vf[n][k2] = *(const short8*)&Vt[n*16 + lm][jb*64 + k2*32 + lk*8];
            }
        // prefetch next jb's bias while this jb computes
        uint2 bb_n[2][4];
        if (jb < 3) {
            #pragma unroll
            for (int m = 0; m < 2; ++m)
                #pragma unroll
                for (int n = 0; n < 4; ++n)
                    bb_n[m][n] = *(const uint2*)(btab + (size_t)((jb+1)*64 + n*16 + lm) * 256 + wq0 + m*16 + lk*4);
        }

        #pragma unroll
        for (int m = 0; m < 2; ++m) {
            f32x4 sv[4];
            __builtin_amdgcn_s_setprio(1);
            #pragma unroll
            for (int n = 0; n < 4; ++n) {
                f32x4 z = (f32x4){0.f,0.f,0.f,0.f};
                sv[n] = __builtin_amdgcn_mfma_f32_16x16x32_bf16(qf[m][0], kf[n][0], z, 0, 0, 0);
                sv[n] = __builtin_amdgcn_mfma_f32_16x16x32_bf16(qf[m][1], kf[n][1], sv[n], 0, 0, 0);
            }
            __builtin_amdgcn_s_setprio(0);
            #pragma unroll
            for (int n = 0; n < 4; ++n) {
                uint2 bb = bb_c[m][n];
                float s0 = fmaf(sv[n][0], SCL, bf2f(bb.x & 0xffffu));
                float s1 = fmaf(sv[n][1], SCL, bf2f(bb.x >> 16));
                float s2 = fmaf(sv[n][2], SCL, bf2f(bb.y & 0xffffu));
                float s3 = fmaf(sv[n][3], SCL, bf2f(bb.y >> 16));
                sv[n][0] = exp2f(fminf(s0, PCLAMP));
                sv[n][1] = exp2f(fminf(s1, PCLAMP));
                sv[n][2] = exp2f(fminf(s2, PCLAMP));
                sv[n][3] = exp2f(fminf(s3, PCLAMP));
            }
            #pragma unroll
            for (int n = 0; n < 4; ++n)
                #pragma unroll
                for (int r = 0; r < 4; ++r) {
                    ushort u = pk2bf(sv[n][r], sv[n][r]).x;   // 1-op cvt
                    lsum[m][r] += bf2f(u);                    // rounded-p denominator
                    Ps[w][lk*4 + r][n*16 + lm] = u;
                }
            short8 pf[2];
            #pragma unroll
            for (int k2 = 0; k2 < 2; ++k2)
                pf[k2] = *(const short8*)&Ps[w][lm][k2*32 + lk*8];
            __builtin_amdgcn_s_setprio(1);
            #pragma unroll
            for (int n = 0; n < 4; ++n) {
                acc_o[m][n] = __builtin_amdgcn_mfma_f32_16x16x32_bf16(pf[0], vf[n][0], acc_o[m][n], 0, 0, 0);
                acc_o[m][n] = __builtin_amdgcn_mfma_f32_16x16x32_bf16(pf[1], vf[n][1], acc_o[m][n], 0, 0, 0);
            }
            __builtin_amdgcn_s_setprio(0);
        }
        if (jb < 3) {
            #pragma unroll
            for (int m = 0; m < 2; ++m)
                #pragma unroll
                for (int n = 0; n < 4; ++n)
                    bb_c[m][n] = bb_n[m][n];
        }
    }

    // epilogue: one cross-lane sum reduce per row, O /= l, tiled store
    #pragma unroll
    for (int m = 0; m < 2; ++m) {
        float inv[4];
        #pragma unroll
        for (int r = 0; r < 4; ++r) {
            float s = lsum[m][r];
            s += __shfl_xor(s, 1);
            s += __shfl_xor(s, 2);
            s += __shfl_xor(s, 4);
            s += __shfl_xor(s, 8);
            inv[r] = 1.f / s;
        }
        #pragma unroll
        for (int r = 0; r < 4; ++r) {
            int q = wq0 + m*16 + lk*4 + r;
            if (q < NTOK) {
                int gm = b * NTOK + q;
                #pragma unroll
                for (int n = 0; n < 4; ++n) {
                    int k = h * DHEAD + n*16 + lm;
                    o_t[tiled_addr(gm, k)] = (uint16_t)f2bf(acc_o[m][n][r] * inv[r]);
                }
            }
        }
    }
}

// =============== Kernel 3: output projection (BM=BN=128) ===================
__global__ __launch_bounds__(256)
void proj_gemm_mfma(const uint16_t* __restrict__ ot, const uint16_t* __restrict__ wp,
                    const float* __restrict__ bias, float* __restrict__ out)
{
    __shared__ ushort Af[3][8][64][8];
    __shared__ ushort Bf[3][8][64][8];
    const int t = threadIdx.x;
    const int w = t >> 6, l = t & 63;
    const int wr = w >> 1, wc = w & 1;
    const int lm = l & 15, lk = l >> 4;

    // grid 1470, chunked-XCD swizzle (q=183, r=6)
    const int bid = blockIdx.x;
    const int xcd = bid & 7;
    const int wg = (xcd < 6 ? xcd * 184 : 1104 + (xcd - 6) * 183) + (bid >> 3);
    const int mtile = wg / 6, ctile = wg - mtile * 6;
    const int m0 = mtile * 128, c0 = ctile * 128;

    const uint16_t* gA0 = ot + ((size_t)(mtile*8 + w    ) * KT * 64 + l) * 8;
    const uint16_t* gA1 = ot + ((size_t)(mtile*8 + w + 4) * KT * 64 + l) * 8;
    const uint16_t* gB0 = wp + ((size_t)(ctile*8 + w    ) * KT * 64 + l) * 8;
    const uint16_t* gB1 = wp + ((size_t)(ctile*8 + w + 4) * KT * 64 + l) * 8;

    f32x4 acc[4][4];
    #pragma unroll
    for (int m = 0; m < 4; ++m)
        #pragma unroll
        for (int n = 0; n < 4; ++n) acc[m][n] = (f32x4){0.f,0.f,0.f,0.f};

    GEMM_LOOP

    float4 bsv[4]; int cArr[4];
    #pragma unroll
    for (int n = 0; n < 4; ++n) {
        cArr[n] = c0 + wc*64 + n*16 + lk*4;
        bsv[n]  = *(const float4*)(bias + cArr[n]);
    }
    #pragma unroll
    for (int m = 0; m < 4; ++m) {
        int gm = m0 + wr*64 + m*16 + lm;
        #pragma unroll
        for (int n = 0; n < 4; ++n) {
            float4 r;
            r.x = acc[m][n][0] + bsv[n].x;
            r.y = acc[m][n][1] + bsv[n].y;
            r.z = acc[m][n][2] + bsv[n].z;
            r.w = acc[m][n][3] + bsv[n].w;
            *(float4*)(out + (size_t)gm * CDIM + cArr[n]) = r;
        }
    }
}

extern "C" void kernel_launch(void* const* d_in, const int* in_sizes, int n_in,
                              void* d_out, int out_size, void* d_ws, size_t ws_size,
                              hipStream_t stream)
{
    (void)n_in; (void)out_size;
    const float* x          = (const float*)d_in[0];
    const float* qkv_w      = (const float*)d_in[1];
    const float* proj_w     = (const float*)d_in[2];
    const float* proj_b     = (const float*)d_in[3];
    const float* bias_table = (const float*)d_in[4];
    const int*   rel        = (const int*)d_in[5];
    const int n_bias = in_sizes[4] / HEADS;

    const size_t qkv_elems = (size_t)BATCH * 3 * HEADS * NTOK * DHEAD;  // 72,253,440
    const size_t o_elems   = (size_t)BATCH * HEADS * NTOK * DHEAD;      // 24,084,480 (= x elems)
    const size_t bt_elems  = (size_t)HEADS * 256 * 256;                 //    786,432
    const size_t wq_elems  = (size_t)3 * CDIM * CDIM;                   //  1,769,472
    const size_t wp_elems  = (size_t)CDIM * CDIM;                       //    589,824

    uint16_t* qkv_ws = (uint16_t*)d_ws;
    uint16_t* o_ws   = qkv_ws + qkv_elems;   // x_tiled until attn overwrites with O_tiled
    uint16_t* bt_ws  = o_ws + o_elems;
    uint16_t* wq_ws  = bt_ws + bt_elems;
    uint16_t* wp_ws  = wq_ws + wq_elems;
    const size_t need = (qkv_elems + o_elems + bt_elems + wq_elems + wp_elems) * sizeof(uint16_t);
    if (ws_size < need) return;   // ~199 MB

    uint16_t* xb = o_ws;

    cvt_all<<<2048, 256, 0, stream>>>(x, qkv_w, proj_w, xb, wq_ws, wp_ws,
                                      bias_table, rel, n_bias, bt_ws);

    qkv_gemm_mfma<<<4410, 256, 0, stream>>>(xb, wq_ws, qkv_ws);

    attn_mfma<<<dim3(BATCH * HEADS), 512, 0, stream>>>(qkv_ws, bt_ws, o_ws);

    proj_gemm_mfma<<<1470, 256, 0, stream>>>(o_ws, wp_ws, proj_b, (float*)d_out);
}